// Round 6
// baseline (2935.672 us; speedup 1.0000x reference)
//
#include <hip/hip_runtime.h>
#include <hip/hip_bf16.h>
#include <math.h>

#define B_   32
#define N_   256
#define S_   257
#define D_   768
#define FF_  3072
#define H_   12
#define HD_  64
#define L_   6
#define NA_  512
#define ND_  512
#define NE_  512
#define NS_  512
#define SCALE_ 0.125f
#define EPS_ 1e-5f
#define NEG_BIG_ (-1e30f)

#define DD_  (D_ * D_)      // 589824
#define FD_  (FF_ * D_)     // 2359296
#define WTOT_ (4 * DD_ + 2 * FD_)  // 7077888
#define QKVN_ 2304          // fused q|k|v output width

typedef __hip_bfloat16 bf16;
typedef __attribute__((ext_vector_type(8))) short bf16x8;
typedef __attribute__((ext_vector_type(4))) float f32x4;

#define AS1 __attribute__((address_space(1)))
#define AS3 __attribute__((address_space(3)))

#define BAR()  asm volatile("s_barrier" ::: "memory")
#define VM0()  asm volatile("s_waitcnt vmcnt(0)" ::: "memory")
#define VM2()  asm volatile("s_waitcnt vmcnt(2)" ::: "memory")
#define VM4()  asm volatile("s_waitcnt vmcnt(4)" ::: "memory")
#define VM6()  asm volatile("s_waitcnt vmcnt(6)" ::: "memory")
#define VM8()  asm volatile("s_waitcnt vmcnt(8)" ::: "memory")

static __device__ __forceinline__ int iclamp(int v, int lo, int hi) {
    return v < lo ? lo : (v > hi ? hi : v);
}
static __device__ __forceinline__ float b2f(bf16 v) { return (float)v; }
static __device__ __forceinline__ short f2b(float f) {
    union { bf16 b; short s; } u; u.b = __float2bfloat16(f); return u.s;
}

// ---------------------------------------------------------------- embedding
__global__ __launch_bounds__(256) void embed_kernel(
    const int* __restrict__ x, const int* __restrict__ indeg,
    const int* __restrict__ outdeg, const float* __restrict__ atom_emb,
    const float* __restrict__ ine, const float* __restrict__ oute,
    const float* __restrict__ gtok, float* __restrict__ h)
{
    int row = blockIdx.x;           // b*S + s
    int b = row / S_, s = row % S_;
    int t = threadIdx.x;
    float* hr = h + (size_t)row * D_;
    if (s == 0) {
        for (int d = t; d < D_; d += 256) hr[d] = gtok[d];
        return;
    }
    int n = s - 1;
    size_t xb = ((size_t)b * N_ + n) * 3;
    int i0 = iclamp(x[xb + 0], 0, NA_);
    int i1 = iclamp(x[xb + 1], 0, NA_);
    int i2 = iclamp(x[xb + 2], 0, NA_);
    int id = iclamp(indeg[(size_t)b * N_ + n], 0, ND_ - 1);
    int od = iclamp(outdeg[(size_t)b * N_ + n], 0, ND_ - 1);
    const float* a0 = atom_emb + (size_t)i0 * D_;
    const float* a1 = atom_emb + (size_t)i1 * D_;
    const float* a2 = atom_emb + (size_t)i2 * D_;
    const float* pi = ine + (size_t)id * D_;
    const float* po = oute + (size_t)od * D_;
    for (int d = t; d < D_; d += 256)
        hr[d] = a0[d] + a1[d] + a2[d] + pi[d] + po[d];
}

// ---------------------------------------------------------------- attn bias
__global__ __launch_bounds__(256) void bias_kernel(
    const int* __restrict__ x, const float* __restrict__ ab,
    const int* __restrict__ sp, const int* __restrict__ et,
    const float* __restrict__ spemb, const float* __restrict__ eemb,
    const float* __restrict__ virt, bf16* __restrict__ bias)
{
    int row = blockIdx.x;           // b*S + q
    int b = row / S_, q = row % S_;
    for (int k = threadIdx.x; k < S_; k += 256) {
        float abv = ab[((size_t)b * S_ + q) * S_ + k];
        bool masked = (k >= 1) && (x[((size_t)b * N_ + (k - 1)) * 3] == 0);
        size_t out_base = (size_t)b * H_ * S_ * S_ + (size_t)q * S_ + k;
        if (masked) {
            #pragma unroll
            for (int hh = 0; hh < H_; hh++)
                bias[out_base + (size_t)hh * S_ * S_] = __float2bfloat16(NEG_BIG_);
        } else if (q == 0 || k == 0) {
            #pragma unroll
            for (int hh = 0; hh < H_; hh++)
                bias[out_base + (size_t)hh * S_ * S_] = __float2bfloat16(abv + virt[hh]);
        } else {
            int spv = iclamp(sp[((size_t)b * N_ + (q - 1)) * N_ + (k - 1)], 0, NS_ - 1);
            size_t eb = (((size_t)b * N_ + (q - 1)) * N_ + (k - 1)) * 3;
            int e0 = iclamp(et[eb + 0], 0, NE_);
            int e1 = iclamp(et[eb + 1], 0, NE_);
            int e2 = iclamp(et[eb + 2], 0, NE_);
            #pragma unroll
            for (int hh = 0; hh < H_; hh++) {
                float inner = spemb[spv * H_ + hh]
                    + (eemb[e0 * H_ + hh] + eemb[e1 * H_ + hh] + eemb[e2 * H_ + hh]) * (1.0f / 3.0f);
                bias[out_base + (size_t)hh * S_ * S_] = __float2bfloat16(abv + inner);
            }
        }
    }
}

// ---------------------------------------------------------------- weight cvt (per layer)
// SCALE_ folded into Wq region so the fused QKV GEMM needs no epilogue scale.
__global__ __launch_bounds__(256) void cvt_w_kernel(
    const float* __restrict__ Wq, const float* __restrict__ Wk,
    const float* __restrict__ Wv, const float* __restrict__ Wo,
    const float* __restrict__ W1, const float* __restrict__ W2,
    int layer, bf16* __restrict__ dst)
{
    size_t i = ((size_t)blockIdx.x * 256 + threadIdx.x) * 8;
    if (i >= (size_t)WTOT_) return;
    const float* src;
    float sc = 1.f;
    if (i < (size_t)4 * DD_) {
        size_t r = i / DD_;
        const float* base = (r == 0) ? Wq : (r == 1) ? Wk : (r == 2) ? Wv : Wo;
        src = base + (size_t)layer * DD_ + (i - r * DD_);
        if (r == 0) sc = SCALE_;
    } else if (i < (size_t)4 * DD_ + FD_) {
        src = W1 + (size_t)layer * FD_ + (i - (size_t)4 * DD_);
    } else {
        src = W2 + (size_t)layer * FD_ + (i - (size_t)4 * DD_ - FD_);
    }
    float4 a = *(const float4*)src;
    float4 c = *(const float4*)(src + 4);
    *(bf16x8*)((short*)dst + i) =
        (bf16x8){f2b(a.x * sc), f2b(a.y * sc), f2b(a.z * sc), f2b(a.w * sc),
                 f2b(c.x * sc), f2b(c.y * sc), f2b(c.z * sc), f2b(c.w * sc)};
}

// pack q|k|v biases for layer into one f32[2304]; SCALE folded into bq part
__global__ __launch_bounds__(256) void pack_bias_kernel(
    const float* __restrict__ bq, const float* __restrict__ bk,
    const float* __restrict__ bv, int layer, float* __restrict__ bqkv)
{
    int i = blockIdx.x * 256 + threadIdx.x;
    if (i >= QKVN_) return;
    float v;
    if (i < D_)            v = bq[layer * D_ + i] * SCALE_;
    else if (i < 2 * D_)   v = bk[layer * D_ + (i - D_)];
    else                   v = bv[layer * D_ + (i - 2 * D_)];
    bqkv[i] = v;
}

// ---------------------------------------------------------------- layernorm (f32 in, bf16 out)
__global__ __launch_bounds__(256) void ln_kernel(
    const float* __restrict__ x, bf16* __restrict__ y,
    const float* __restrict__ g, const float* __restrict__ b)
{
    int row = blockIdx.x;
    int t = threadIdx.x;
    const float* xr = x + (size_t)row * D_;
    bf16* yr = y + (size_t)row * D_;
    float v0 = xr[t], v1 = xr[t + 256], v2 = xr[t + 512];
    __shared__ float rs[256], rq[256];
    rs[t] = v0 + v1 + v2;
    rq[t] = v0 * v0 + v1 * v1 + v2 * v2;
    __syncthreads();
    for (int o = 128; o > 0; o >>= 1) {
        if (t < o) { rs[t] += rs[t + o]; rq[t] += rq[t + o]; }
        __syncthreads();
    }
    float mean = rs[0] * (1.0f / D_);
    float var = fmaxf(rq[0] * (1.0f / D_) - mean * mean, 0.f);
    float inv = rsqrtf(var + EPS_);
    yr[t]       = __float2bfloat16((v0 - mean) * inv * g[t]       + b[t]);
    yr[t + 256] = __float2bfloat16((v1 - mean) * inv * g[t + 256] + b[t + 256]);
    yr[t + 512] = __float2bfloat16((v2 - mean) * inv * g[t + 512] + b[t + 512]);
}

// ---------------------------------------------------------------- final LN + split
__global__ __launch_bounds__(256) void final_ln_kernel(
    const float* __restrict__ x, const float* __restrict__ g,
    const float* __restrict__ b, float* __restrict__ out)
{
    int row = blockIdx.x;
    int bb = row / S_, s = row % S_;
    int t = threadIdx.x;
    const float* xr = x + (size_t)row * D_;
    float v0 = xr[t], v1 = xr[t + 256], v2 = xr[t + 512];
    __shared__ float rs[256], rq[256];
    rs[t] = v0 + v1 + v2;
    rq[t] = v0 * v0 + v1 * v1 + v2 * v2;
    __syncthreads();
    for (int o = 128; o > 0; o >>= 1) {
        if (t < o) { rs[t] += rs[t + o]; rq[t] += rq[t + o]; }
        __syncthreads();
    }
    float mean = rs[0] * (1.0f / D_);
    float var = fmaxf(rq[0] * (1.0f / D_) - mean * mean, 0.f);
    float inv = rsqrtf(var + EPS_);
    float* dst = (s == 0) ? out + (size_t)B_ * N_ * D_ + (size_t)bb * D_
                          : out + ((size_t)bb * N_ + (s - 1)) * D_;
    dst[t]       = (v0 - mean) * inv * g[t]       + b[t];
    dst[t + 256] = (v1 - mean) * inv * g[t + 256] + b[t + 256];
    dst[t + 512] = (v2 - mean) * inv * g[t + 512] + b[t + 512];
}

// ---------------------------------------------------------------- 256-wide MFMA GEMM
// C[m,n] = sum_k A[m,k]*W[n,k] + bias[n].  BM=256, BN=256|128, BK=64.
// 512 threads = 8 waves (2 M x 4 N); per-wave 128 x (BN/4); acc[8][BN/64].
// 4 phases per K-tile: phase q reads A 16-row segments {2q, 2q+1} per half
// (+ all B at q0). A chunks (64-row quarters) 0,2 are read at q0/q1;
// chunks 1,3 at q2/q3.
// Counted-vmcnt schedule (per-wave ledger, wave-symmetric so barrier
// propagates each wave's own confirmation to all):
//  group g (tile T, buf c=g&1), loads/group = 8 (BN=256) | 6 (BN=128):
//   q0: stage A(T+1) ch1,3 -> buf c^1     (region read q2/q3 of g-1: free)
//   q1: stage B(T+2) ch0,1 -> buf c       (B(c) read only at q0: free)
//   q2: stage B(T+2) ch2,3 (BN=256 only)
//   q3: stage A(T+2) ch0,2 -> buf c       (read q0/q1 this group: free)
//  waits: q1-end VM8|VM6 confirms A(T) ch1,3 before q2 reads them
//         (BN=128 NEEDS VM6: at g==nt-2 queue is only 8 -> VM8 is a no-op
//          -> stale-LDS race; VM6 verified safe at all groups);
//         q3-end VM8|VM6 confirms B(T+1)+A(T+1)ch0,2 before next group.
//  tail: q3-end VM2 at g==nt-2; q1-end VM0 at g==nt-1. Queue invariant
//  (8|6 in flight entering each group) verified incl. prologue + tails.
// LDS swizzle: physical 16B-granule = logical ^ (row&7) on BOTH the
// pre-swizzled global source (global_load_lds writes linearly) and the
// ds_read address -> 2-way (free) bank aliasing (0-conflict, round 4).
// MODE 0: plain  2: exact gelu  3: + res[m,n] (f32)
// A rows >= M are read (garbage, within workspace) but never stored.
template <int BN, int MODE, typename TC>
__global__ __launch_bounds__(512, 1) void mgemm2(
    const bf16* __restrict__ A, const bf16* __restrict__ W,
    const float* __restrict__ bias, const float* __restrict__ res,
    TC* __restrict__ C, int M, int N, int K, int gx)
{
    constexpr int NTW = BN / 64;        // n-tiles per wave (4 | 2)
    constexpr int WN  = BN / 4;         // per-wave N extent (64 | 32)
    constexpr int BCH = BN / 64;        // B stage chunks per tile (4 | 2)
    constexpr int BSZ = BN * 64;        // shorts per B buffer

    __shared__ short Asm[2][256 * 64];
    __shared__ short Bsm[2][BSZ];
    AS3 short* AsL = (AS3 short*)&Asm[0][0];
    AS3 short* BsL = (AS3 short*)&Bsm[0][0];

    const int t = threadIdx.x;
    const int lane = t & 63;
    const int wid = t >> 6;             // 0..7
    const int wm = wid >> 2;            // 0..1
    const int wn = wid & 3;             // 0..3
    const int quad = lane >> 4;
    const int col16 = lane & 15;
    const int r7 = col16 & 7;

    // bijective XCD swizzle
    const int nwg = gridDim.x;
    const int orig = blockIdx.x;
    const int q8 = nwg >> 3, r8 = nwg & 7;
    const int xcd = orig & 7, li = orig >> 3;
    const int wgid = (xcd < r8 ? xcd * (q8 + 1) : r8 * (q8 + 1) + (xcd - r8) * q8) + li;
    const int block_m = (wgid % gx) * 256;
    const int block_n = (wgid / gx) * BN;

    // stage-side per-lane constants: dest granule (lane&7) of row r holds
    // logical granule (lane&7)^(r&7); r&7 == lane>>3 for our chunk mapping.
    const int lgb = ((lane & 7) ^ (lane >> 3)) * 8;   // shorts

    auto stA = [&](int db, int T, int chunk) {        // one 64-row quarter
        int row = chunk * 64 + wid * 8 + (lane >> 3);
        const bf16* src = A + (size_t)(block_m + row) * K + T * 64 + lgb;
        __builtin_amdgcn_global_load_lds((const AS1 void*)src,
            (AS3 void*)(AsL + db * 16384 + (chunk * 512 + wid * 64) * 8), 16, 0, 0);
    };
    auto stB = [&](int db, int T, int chunk) {
        int row = chunk * 64 + wid * 8 + (lane >> 3);
        const bf16* src = W + (size_t)(block_n + row) * K + T * 64 + lgb;
        __builtin_amdgcn_global_load_lds((const AS1 void*)src,
            (AS3 void*)(BsL + db * BSZ + (chunk * 512 + wid * 64) * 8), 16, 0, 0);
    };

    f32x4 acc[8][NTW];
    #pragma unroll
    for (int i = 0; i < 8; i++)
        #pragma unroll
        for (int j = 0; j < NTW; j++)
            acc[i][j] = (f32x4){0.f, 0.f, 0.f, 0.f};

    const int nt = K >> 6;              // K-tiles (>= 12 at all call sites)

    // prologue: tile0 full; tile1 = B full + A-quarters 0,2
    stA(0, 0, 0); stA(0, 0, 1); stA(0, 0, 2); stA(0, 0, 3);
    #pragma unroll
    for (int ch = 0; ch < BCH; ch++) stB(0, 0, ch);
    #pragma unroll
    for (int ch = 0; ch < BCH; ch++) stB(1, 1, ch);
    stA(1, 1, 0); stA(1, 1, 2);
    if constexpr (BCH == 4) VM6(); else VM4();   // tile0 confirmed; rest in flight
    BAR();

    for (int g = 0; g < nt; ++g) {
        const int c = g & 1;

        // ================ phase q0 ================
        if (g + 1 < nt) { stA(c ^ 1, g + 1, 1); stA(c ^ 1, g + 1, 3); }
        bf16x8 bfr[NTW][2];
        #pragma unroll
        for (int j = 0; j < NTW; j++)
            #pragma unroll
            for (int ks = 0; ks < 2; ks++)
                bfr[j][ks] = *(const bf16x8*)&Bsm[c][(wn * WN + j * 16 + col16) * 64 + ((ks * 4 + quad) ^ r7) * 8];
        {
            bf16x8 a0[2], a1[2];
            #pragma unroll
            for (int ks = 0; ks < 2; ks++) {
                a0[ks] = *(const bf16x8*)&Asm[c][(wm * 128 + 0 * 16 + col16) * 64 + ((ks * 4 + quad) ^ r7) * 8];
                a1[ks] = *(const bf16x8*)&Asm[c][(wm * 128 + 1 * 16 + col16) * 64 + ((ks * 4 + quad) ^ r7) * 8];
            }
            #pragma unroll
            for (int j = 0; j < NTW; j++)
                #pragma unroll
                for (int ks = 0; ks < 2; ks++) {
                    acc[0][j] = __builtin_amdgcn_mfma_f32_16x16x32_bf16(a0[ks], bfr[j][ks], acc[0][j], 0, 0, 0);
                    acc[1][j] = __builtin_amdgcn_mfma_f32_16x16x32_bf16(a1[ks], bfr[j][ks], acc[1][j], 0, 0, 0);
                }
        }
        BAR();

        // ================ phase q1 ================
        if (g + 2 < nt) { stB(c, g + 2, 0); stB(c, g + 2, 1); }
        {
            bf16x8 a0[2], a1[2];
            #pragma unroll
            for (int ks = 0; ks < 2; ks++) {
                a0[ks] = *(const bf16x8*)&Asm[c][(wm * 128 + 2 * 16 + col16) * 64 + ((ks * 4 + quad) ^ r7) * 8];
                a1[ks] = *(const bf16x8*)&Asm[c][(wm * 128 + 3 * 16 + col16) * 64 + ((ks * 4 + quad) ^ r7) * 8];
            }
            #pragma unroll
            for (int j = 0; j < NTW; j++)
                #pragma unroll
                for (int ks = 0; ks < 2; ks++) {
                    acc[2][j] = __builtin_amdgcn_mfma_f32_16x16x32_bf16(a0[ks], bfr[j][ks], acc[2][j], 0, 0, 0);
                    acc[3][j] = __builtin_amdgcn_mfma_f32_16x16x32_bf16(a1[ks], bfr[j][ks], acc[3][j], 0, 0, 0);
                }
        }
        if (g == nt - 1) VM0();
        else { if constexpr (BCH == 4) VM8(); else VM6(); }   // gates A(T) ch1,3
        BAR();

        // ================ phase q2 ================
        if constexpr (BCH == 4) {
            if (g + 2 < nt) { stB(c, g + 2, 2); stB(c, g + 2, 3); }
        }
        {
            bf16x8 a0[2], a1[2];
            #pragma unroll
            for (int ks = 0; ks < 2; ks++) {
                a0[ks] = *(const bf16x8*)&Asm[c][(wm * 128 + 4 * 16 + col16) * 64 + ((ks * 4 + quad) ^ r7) * 8];
                a1[ks] = *(const bf16x8*)&Asm[c][(wm * 128 + 5 * 16 + col16) * 64 + ((ks * 4 + quad) ^ r7) * 8];
            }
            #pragma unroll
            for (int j = 0; j < NTW; j++)
                #pragma unroll
                for (int ks = 0; ks < 2; ks++) {
                    acc[4][j] = __builtin_amdgcn_mfma_f32_16x16x32_bf16(a0[ks], bfr[j][ks], acc[4][j], 0, 0, 0);
                    acc[5][j] = __builtin_amdgcn_mfma_f32_16x16x32_bf16(a1[ks], bfr[j][ks], acc[5][j], 0, 0, 0);
                }
        }
        BAR();

        // ================ phase q3 ================
        if (g + 2 < nt) { stA(c, g + 2, 0); stA(c, g + 2, 2); }
        {
            bf16x8 a0[2], a1[2];
            #pragma unroll
            for (int ks = 0; ks < 2; ks++) {
                a0[ks] = *(const bf16x8*)&Asm[c][(wm * 128 + 6 * 16 + col16) * 64 + ((ks * 4 + quad) ^ r7) * 8];
                a1[ks] = *(const bf16x8*)&Asm[c][(wm * 128 + 7 * 16 + col16) * 64 + ((ks * 4 + quad) ^ r7) * 8];
            }
            #pragma unroll
            for (int j = 0; j < NTW; j++)
                #pragma unroll
                for (int ks = 0; ks < 2; ks++) {
                    acc[6][j] = __builtin_amdgcn_mfma_f32_16x16x32_bf16(a0[ks], bfr[j][ks], acc[6][j], 0, 0, 0);
                    acc[7][j] = __builtin_amdgcn_mfma_f32_16x16x32_bf16(a1[ks], bfr[j][ks], acc[7][j], 0, 0, 0);
                }
        }
        if (g == nt - 2) { VM2(); }
        else if (g < nt - 2) { if constexpr (BCH == 4) VM8(); else VM6(); }
        BAR();
    }

    // epilogue: D row = quad*4 + r, col = col16
    #pragma unroll
    for (int mt = 0; mt < 8; mt++) {
        #pragma unroll
        for (int j = 0; j < NTW; j++) {
            int gn = block_n + wn * WN + j * 16 + col16;
            float bn = bias[gn];
            #pragma unroll
            for (int r = 0; r < 4; r++) {
                int gm = block_m + wm * 128 + mt * 16 + quad * 4 + r;
                if (gm < M) {
                    float val = acc[mt][j][r] + bn;
                    if (MODE == 2) val = 0.5f * val * (1.0f + erff(val * 0.70710678118654752f));
                    if (MODE == 3) val += res[(size_t)gm * N + gn];
                    C[(size_t)gm * N + gn] = (TC)val;
                }
            }
        }
    }
}

// ---------------------------------------------------------------- MFMA flash attention
// grid (5 q-tiles of 64, B*H). 4 waves/block, each wave owns 16 q rows.
// Q/K/V live in the fused qkv buffer: row stride QKVN_, offsets 0/768/1536.
__global__ __launch_bounds__(256) void attn_mfma(
    const bf16* __restrict__ qkv, const bf16* __restrict__ bias,
    bf16* __restrict__ ob)
{
    const bf16* qb = qkv;
    const bf16* kb = qkv + D_;
    const bf16* vb = qkv + 2 * D_;
    // stride 72 shorts = 144 B rows: 16B-aligned b128 frags, even bank spread
    __shared__ short Ks[64 * 72];        // K[k_loc][d]
    __shared__ short Vt[64 * 72];        // V^T[d][k_loc]
    __shared__ short Ps[4][16 * 72];     // per-wave P tile [q_loc][k_loc]

    const int t = threadIdx.x;
    const int lane = t & 63;
    const int wq = t >> 6;               // wave id = q sub-tile
    const int quad = lane >> 4;
    const int col = lane & 15;
    const int bh = blockIdx.y;
    const int hh = bh % H_;
    const int b = bh / H_;
    const int q0 = blockIdx.x * 64;

    // ---- Q fragments: A-operand row = col (q in tile), k-offset = quad*8 + kk*32
    bf16x8 qf[2];
    {
        int qrow = q0 + wq * 16 + col;
        #pragma unroll
        for (int kk = 0; kk < 2; kk++) {
            bf16x8 v = (bf16x8){0, 0, 0, 0, 0, 0, 0, 0};
            if (qrow < S_)
                v = *(const bf16x8*)(qb + ((size_t)(b * S_ + qrow)) * QKVN_ + hh * HD_ + kk * 32 + quad * 8);
            qf[kk] = v;
        }
    }

    f32x4 o_acc[4];
    #pragma unroll
    for (int nt = 0; nt < 4; nt++) o_acc[nt] = (f32x4){0.f, 0.f, 0.f, 0.f};
    float m_run[4], l_run[4];
    #pragma unroll
    for (int r = 0; r < 4; r++) { m_run[r] = NEG_BIG_; l_run[r] = 0.f; }

    for (int kc = 0; kc < 5; kc++) {
        const int kbase = kc * 64;
        // ---- stage K chunk (64 rows x 64 d), zero-fill OOR rows
        #pragma unroll
        for (int ss = 0; ss < 2; ss++) {
            int s = t + ss * 256;
            int row = s >> 3, dg = (s & 7) * 8;
            int gk = kbase + row;
            bf16x8 v = (bf16x8){0, 0, 0, 0, 0, 0, 0, 0};
            if (gk < S_)
                v = *(const bf16x8*)(kb + ((size_t)(b * S_ + gk)) * QKVN_ + hh * HD_ + dg);
            *(bf16x8*)&Ks[row * 72 + dg] = v;
        }
        // ---- stage V^T: lane -> (d = wq*16 + col, kp = ss*4 + quad), 2 keys / b32
        {
            int d = wq * 16 + col;
            const bf16* vcol = vb + ((size_t)(b * S_)) * QKVN_ + hh * HD_ + d;
            #pragma unroll
            for (int ss = 0; ss < 8; ss++) {
                int kp = ss * 4 + quad;          // 0..31
                int gk = kbase + kp * 2;
                short v0 = (gk     < S_) ? *(const short*)(vcol + (size_t)gk * QKVN_)       : (short)0;
                short v1 = (gk + 1 < S_) ? *(const short*)(vcol + (size_t)(gk + 1) * QKVN_) : (short)0;
                unsigned pk = ((unsigned)(unsigned short)v0) |
                              ((unsigned)(unsigned short)v1 << 16);
                *(unsigned*)&Vt[d * 72 + kp * 2] = pk;
            }
        }
        __syncthreads();

        // ---- S = Q K^T (contract over d)
        f32x4 s_acc[4];
        #pragma unroll
        for (int nt = 0; nt < 4; nt++) s_acc[nt] = (f32x4){0.f, 0.f, 0.f, 0.f};
        #pragma unroll
        for (int nt = 0; nt < 4; nt++) {
            #pragma unroll
            for (int kk = 0; kk < 2; kk++) {
                bf16x8 kfrag = *(const bf16x8*)&Ks[(nt * 16 + col) * 72 + kk * 32 + quad * 8];
                s_acc[nt] = __builtin_amdgcn_mfma_f32_16x16x32_bf16(qf[kk], kfrag, s_acc[nt], 0, 0, 0);
            }
        }

        // ---- bias + OOR key mask (C layout: row = quad*4+r, col = k in tile)
        const int qrow_base = q0 + wq * 16 + quad * 4;
        #pragma unroll
        for (int nt = 0; nt < 4; nt++) {
            int kglob = kbase + nt * 16 + col;
            #pragma unroll
            for (int r = 0; r < 4; r++) {
                int q = qrow_base + r;
                float sv = s_acc[nt][r];
                if (kglob >= S_)       sv = NEG_BIG_;
                else if (q < S_)       sv += b2f(bias[((size_t)bh * S_ + q) * S_ + kglob]);
                s_acc[nt][r] = sv;
            }
        }

        // ---- online softmax: rows live on the 16 lanes sharing quad
        float alpha[4];
        #pragma unroll
        for (int r = 0; r < 4; r++) {
            float mx = fmaxf(fmaxf(s_acc[0][r], s_acc[1][r]),
                             fmaxf(s_acc[2][r], s_acc[3][r]));
            #pragma unroll
            for (int off = 8; off; off >>= 1) mx = fmaxf(mx, __shfl_xor(mx, off));
            float m_new = fmaxf(m_run[r], mx);
            alpha[r] = __expf(m_run[r] - m_new);
            m_run[r] = m_new;
            float ps = 0.f;
            #pragma unroll
            for (int nt = 0; nt < 4; nt++) {
                float p = __expf(s_acc[nt][r] - m_new);
                s_acc[nt][r] = p;
                ps += p;
            }
            #pragma unroll
            for (int off = 8; off; off >>= 1) ps += __shfl_xor(ps, off);
            l_run[r] = l_run[r] * alpha[r] + ps;
        }

        // ---- P -> per-wave LDS (wave-synchronous write->read), rescale O
        #pragma unroll
        for (int nt = 0; nt < 4; nt++)
            #pragma unroll
            for (int r = 0; r < 4; r++)
                Ps[wq][(quad * 4 + r) * 72 + nt * 16 + col] = f2b(s_acc[nt][r]);
        #pragma unroll
        for (int nt = 0; nt < 4; nt++)
            #pragma unroll
            for (int r = 0; r < 4; r++)
                o_acc[nt][r] *= alpha[r];

        // ---- O += P V (contract over k; B-operand = V^T rows = d)
        bf16x8 pf[2];
        pf[0] = *(const bf16x8*)&Ps[wq][col * 72 + quad * 8];
        pf[1] = *(const bf16x8*)&Ps[wq][col * 72 + 32 + quad * 8];
        #pragma unroll
        for (int nt = 0; nt < 4; nt++) {
            #pragma unroll
            for (int kk = 0; kk < 2; kk++) {
                bf16x8 vfrag = *(const bf16x8*)&Vt[(nt * 16 + col) * 72 + kk * 32 + quad * 8];
                o_acc[nt] = __builtin_amdgcn_mfma_f32_16x16x32_bf16(pf[kk], vfrag, o_acc[nt], 0, 0, 0);
            }
        }
        __syncthreads();
    }

    // ---- epilogue: O / l  (bf16 out, stride D_)
    const int qrow_base = q0 + wq * 16 + quad * 4;
    #pragma unroll
    for (int r = 0; r < 4; r++) {
        int q = qrow_base + r;
        if (q >= S_) continue;
        float invl = 1.0f / l_run[r];
        bf16* orow = ob + ((size_t)(b * S_ + q)) * D_ + hh * HD_;
        #pragma unroll
        for (int nt = 0; nt < 4; nt++)
            orow[nt * 16 + col] = __float2bfloat16(o_acc[nt][r] * invl);
    }
}

// ---------------------------------------------------------------- launch
extern "C" void kernel_launch(void* const* d_in, const int* in_sizes, int n_in,
                              void* d_out, int out_size, void* d_ws, size_t ws_size,
                              hipStream_t stream)
{
    const int*   x         = (const int*)d_in[0];
    const float* attn_bias = (const float*)d_in[1];
    const int*   spatial   = (const int*)d_in[2];
    const int*   edget     = (const int*)d_in[3];
    const int*   indeg     = (const int*)d_in[4];
    const int*   outdeg    = (const int*)d_in[5];
    const float* atom_emb  = (const float*)d_in[6];
    const float* ine       = (const float*)d_in[7];
    const float* oute      = (const float*)d_in[8];
    const float* gtok      = (const float*)d_in[9];
    const float* spemb     = (const float*)d_in[10];
    const float* eemb      = (const float*)d_in[11];
    const float* virt      = (const float*)d_in[12];
    const float* Wq        = (const float*)d_in[13];
    const float* Wk        = (const float*)d_in[14];
    const float* Wv        = (const float*)d_in[15];
    const float* Wo        = (const float*)d_in[16];
    const float* bq        = (const float*)d_in[17];
    const float* bk        = (const float*)d_in[18];
    const float* bvv       = (const float*)d_in[19];
    const float* bo        = (const float*)d_in[20];
    const float* ln1g      = (const float*)d_in[21];
    const float* ln1b      = (const float*)d_in[22];
    const float* ln2g      = (const float*)d_in[23];
    const float* ln2b      = (const float*)d_in[24];
    const float* W1        = (const float*)d_in[25];
    const float* b1        = (const float*)d_in[26];
    const float* W2        = (const float*)d_in[27];
    const float* b2        = (const float*)d_in[28];
    const float* fing      = (const float*)d_in[29];
    const float* finb      = (const float*)d_in[30];

    const int M = B_ * S_;          // 8224
    char* wsp = (char*)d_ws;
    size_t off = 0;
    auto alloc = [&](size_t bytes) -> void* {
        void* p = (void*)(wsp + off);
        off += (bytes + 255) & ~(size_t)255;
        return p;
    };
    // ws: h 25.3 + z 12.6 + qkv/ff 50.6 + bias 50.7 + wbf 14.2 + bqkv = ~153 MB
    float* h    = (float*)alloc((size_t)M * D_ * 4);
    bf16*  z    = (bf16*)alloc((size_t)M * D_ * 2);        // also obuf (bf16)
    bf16*  qkv  = (bf16*)alloc((size_t)M * FF_ * 2);       // fused q|k|v, reused as fbuf
    bf16*  bias = (bf16*)alloc((size_t)B_ * H_ * S_ * S_ * 2);
    bf16*  wbf  = (bf16*)alloc((size_t)WTOT_ * 2);         // per-layer bf16 weights
    float* bqkv = (float*)alloc((size_t)QKVN_ * 4);        // packed q|k|v bias
    bf16* fbuf = qkv;                                      // qkv dead after attn
    bf16* obuf = z;                                        // z dead after QKV GEMM

    embed_kernel<<<M, 256, 0, stream>>>(x, indeg, outdeg, atom_emb, ine, oute, gtok, h);
    bias_kernel<<<M, 256, 0, stream>>>(x, attn_bias, spatial, edget, spemb, eemb, virt, bias);

    const int gx = (M + 255) / 256;        // 33
    const int nQKV = gx * (QKVN_ / 256);   // 33 x 9  = 297
    const int nD   = gx * (D_ / 128);      // 33 x 6  = 198  (BN=128)
    const int nF   = gx * (FF_ / 256);     // 33 x 12 = 396
    dim3 gA(5, B_ * H_);                   // 5 q-tiles of 64 x 384
    const int cvtBlocks = WTOT_ / 2048;    // 3456

    for (int l = 0; l < L_; l++) {
        cvt_w_kernel<<<cvtBlocks, 256, 0, stream>>>(Wq, Wk, Wv, Wo, W1, W2, l, wbf);
        pack_bias_kernel<<<9, 256, 0, stream>>>(bq, bk, bvv, l, bqkv);
        ln_kernel<<<M, 256, 0, stream>>>(h, z, ln1g + l * D_, ln1b + l * D_);
        // fused QKV: W = [Wq*SCALE ; Wk ; Wv] rows, N = 2304
        mgemm2<256, 0, bf16><<<nQKV, 512, 0, stream>>>(z, wbf, bqkv, nullptr, qkv, M, QKVN_, D_, gx);
        attn_mfma<<<gA, 256, 0, stream>>>(qkv, bias, obuf);
        mgemm2<128, 3, float><<<nD, 512, 0, stream>>>(obuf, wbf + 3 * DD_, bo + l * D_, h, h, M, D_, D_, gx);
        ln_kernel<<<M, 256, 0, stream>>>(h, z, ln2g + l * D_, ln2b + l * D_);
        mgemm2<256, 2, bf16><<<nF, 512, 0, stream>>>(z, wbf + 4 * DD_, b1 + l * FF_, nullptr, fbuf, M, FF_, D_, gx);
        mgemm2<128, 3, float><<<nD, 512, 0, stream>>>(fbuf, wbf + 4 * DD_ + FD_, b2 + l * D_, h, h, M, D_, FF_, gx);
    }
    final_ln_kernel<<<M, 256, 0, stream>>>(h, fing, finb, (float*)d_out);
}

// Round 7
// 2459.145 us; speedup vs baseline: 1.1938x; 1.1938x over previous
//
#include <hip/hip_runtime.h>
#include <hip/hip_bf16.h>
#include <math.h>

#define B_   32
#define N_   256
#define S_   257
#define D_   768
#define FF_  3072
#define H_   12
#define HD_  64
#define L_   6
#define NA_  512
#define ND_  512
#define NE_  512
#define NS_  512
#define SCALE_ 0.125f
#define EPS_ 1e-5f
#define NEG_BIG_ (-1e30f)

#define DD_  (D_ * D_)      // 589824
#define FD_  (FF_ * D_)     // 2359296
#define WTOT_ (4 * DD_ + 2 * FD_)  // 7077888
#define QKVN_ 2304          // fused q|k|v output width

typedef __hip_bfloat16 bf16;
typedef __attribute__((ext_vector_type(8))) short bf16x8;
typedef __attribute__((ext_vector_type(4))) float f32x4;

#define AS1 __attribute__((address_space(1)))
#define AS3 __attribute__((address_space(3)))

static __device__ __forceinline__ int iclamp(int v, int lo, int hi) {
    return v < lo ? lo : (v > hi ? hi : v);
}
static __device__ __forceinline__ float b2f(bf16 v) { return (float)v; }
static __device__ __forceinline__ short f2b(float f) {
    union { bf16 b; short s; } u; u.b = __float2bfloat16(f); return u.s;
}

// ---------------------------------------------------------------- embedding
__global__ __launch_bounds__(256) void embed_kernel(
    const int* __restrict__ x, const int* __restrict__ indeg,
    const int* __restrict__ outdeg, const float* __restrict__ atom_emb,
    const float* __restrict__ ine, const float* __restrict__ oute,
    const float* __restrict__ gtok, float* __restrict__ h)
{
    int row = blockIdx.x;           // b*S + s
    int b = row / S_, s = row % S_;
    int t = threadIdx.x;
    float* hr = h + (size_t)row * D_;
    if (s == 0) {
        for (int d = t; d < D_; d += 256) hr[d] = gtok[d];
        return;
    }
    int n = s - 1;
    size_t xb = ((size_t)b * N_ + n) * 3;
    int i0 = iclamp(x[xb + 0], 0, NA_);
    int i1 = iclamp(x[xb + 1], 0, NA_);
    int i2 = iclamp(x[xb + 2], 0, NA_);
    int id = iclamp(indeg[(size_t)b * N_ + n], 0, ND_ - 1);
    int od = iclamp(outdeg[(size_t)b * N_ + n], 0, ND_ - 1);
    const float* a0 = atom_emb + (size_t)i0 * D_;
    const float* a1 = atom_emb + (size_t)i1 * D_;
    const float* a2 = atom_emb + (size_t)i2 * D_;
    const float* pi = ine + (size_t)id * D_;
    const float* po = oute + (size_t)od * D_;
    for (int d = t; d < D_; d += 256)
        hr[d] = a0[d] + a1[d] + a2[d] + pi[d] + po[d];
}

// ---------------------------------------------------------------- attn bias
__global__ __launch_bounds__(256) void bias_kernel(
    const int* __restrict__ x, const float* __restrict__ ab,
    const int* __restrict__ sp, const int* __restrict__ et,
    const float* __restrict__ spemb, const float* __restrict__ eemb,
    const float* __restrict__ virt, bf16* __restrict__ bias)
{
    int row = blockIdx.x;           // b*S + q
    int b = row / S_, q = row % S_;
    for (int k = threadIdx.x; k < S_; k += 256) {
        float abv = ab[((size_t)b * S_ + q) * S_ + k];
        bool masked = (k >= 1) && (x[((size_t)b * N_ + (k - 1)) * 3] == 0);
        size_t out_base = (size_t)b * H_ * S_ * S_ + (size_t)q * S_ + k;
        if (masked) {
            #pragma unroll
            for (int hh = 0; hh < H_; hh++)
                bias[out_base + (size_t)hh * S_ * S_] = __float2bfloat16(NEG_BIG_);
        } else if (q == 0 || k == 0) {
            #pragma unroll
            for (int hh = 0; hh < H_; hh++)
                bias[out_base + (size_t)hh * S_ * S_] = __float2bfloat16(abv + virt[hh]);
        } else {
            int spv = iclamp(sp[((size_t)b * N_ + (q - 1)) * N_ + (k - 1)], 0, NS_ - 1);
            size_t eb = (((size_t)b * N_ + (q - 1)) * N_ + (k - 1)) * 3;
            int e0 = iclamp(et[eb + 0], 0, NE_);
            int e1 = iclamp(et[eb + 1], 0, NE_);
            int e2 = iclamp(et[eb + 2], 0, NE_);
            #pragma unroll
            for (int hh = 0; hh < H_; hh++) {
                float inner = spemb[spv * H_ + hh]
                    + (eemb[e0 * H_ + hh] + eemb[e1 * H_ + hh] + eemb[e2 * H_ + hh]) * (1.0f / 3.0f);
                bias[out_base + (size_t)hh * S_ * S_] = __float2bfloat16(abv + inner);
            }
        }
    }
}

// ---------------------------------------------------------------- weight cvt (per layer)
// SCALE_ folded into Wq region so the fused QKV GEMM needs no epilogue scale.
__global__ __launch_bounds__(256) void cvt_w_kernel(
    const float* __restrict__ Wq, const float* __restrict__ Wk,
    const float* __restrict__ Wv, const float* __restrict__ Wo,
    const float* __restrict__ W1, const float* __restrict__ W2,
    int layer, bf16* __restrict__ dst)
{
    size_t i = ((size_t)blockIdx.x * 256 + threadIdx.x) * 8;
    if (i >= (size_t)WTOT_) return;
    const float* src;
    float sc = 1.f;
    if (i < (size_t)4 * DD_) {
        size_t r = i / DD_;
        const float* base = (r == 0) ? Wq : (r == 1) ? Wk : (r == 2) ? Wv : Wo;
        src = base + (size_t)layer * DD_ + (i - r * DD_);
        if (r == 0) sc = SCALE_;
    } else if (i < (size_t)4 * DD_ + FD_) {
        src = W1 + (size_t)layer * FD_ + (i - (size_t)4 * DD_);
    } else {
        src = W2 + (size_t)layer * FD_ + (i - (size_t)4 * DD_ - FD_);
    }
    float4 a = *(const float4*)src;
    float4 c = *(const float4*)(src + 4);
    *(bf16x8*)((short*)dst + i) =
        (bf16x8){f2b(a.x * sc), f2b(a.y * sc), f2b(a.z * sc), f2b(a.w * sc),
                 f2b(c.x * sc), f2b(c.y * sc), f2b(c.z * sc), f2b(c.w * sc)};
}

// pack q|k|v biases for layer into one f32[2304]; SCALE folded into bq part
__global__ __launch_bounds__(256) void pack_bias_kernel(
    const float* __restrict__ bq, const float* __restrict__ bk,
    const float* __restrict__ bv, int layer, float* __restrict__ bqkv)
{
    int i = blockIdx.x * 256 + threadIdx.x;
    if (i >= QKVN_) return;
    float v;
    if (i < D_)            v = bq[layer * D_ + i] * SCALE_;
    else if (i < 2 * D_)   v = bk[layer * D_ + (i - D_)];
    else                   v = bv[layer * D_ + (i - 2 * D_)];
    bqkv[i] = v;
}

// ---------------------------------------------------------------- layernorm (f32 in, bf16 out)
__global__ __launch_bounds__(256) void ln_kernel(
    const float* __restrict__ x, bf16* __restrict__ y,
    const float* __restrict__ g, const float* __restrict__ b)
{
    int row = blockIdx.x;
    int t = threadIdx.x;
    const float* xr = x + (size_t)row * D_;
    bf16* yr = y + (size_t)row * D_;
    float v0 = xr[t], v1 = xr[t + 256], v2 = xr[t + 512];
    __shared__ float rs[256], rq[256];
    rs[t] = v0 + v1 + v2;
    rq[t] = v0 * v0 + v1 * v1 + v2 * v2;
    __syncthreads();
    for (int o = 128; o > 0; o >>= 1) {
        if (t < o) { rs[t] += rs[t + o]; rq[t] += rq[t + o]; }
        __syncthreads();
    }
    float mean = rs[0] * (1.0f / D_);
    float var = fmaxf(rq[0] * (1.0f / D_) - mean * mean, 0.f);
    float inv = rsqrtf(var + EPS_);
    yr[t]       = __float2bfloat16((v0 - mean) * inv * g[t]       + b[t]);
    yr[t + 256] = __float2bfloat16((v1 - mean) * inv * g[t + 256] + b[t + 256]);
    yr[t + 512] = __float2bfloat16((v2 - mean) * inv * g[t + 512] + b[t + 512]);
}

// ---------------------------------------------------------------- final LN + split
__global__ __launch_bounds__(256) void final_ln_kernel(
    const float* __restrict__ x, const float* __restrict__ g,
    const float* __restrict__ b, float* __restrict__ out)
{
    int row = blockIdx.x;
    int bb = row / S_, s = row % S_;
    int t = threadIdx.x;
    const float* xr = x + (size_t)row * D_;
    float v0 = xr[t], v1 = xr[t + 256], v2 = xr[t + 512];
    __shared__ float rs[256], rq[256];
    rs[t] = v0 + v1 + v2;
    rq[t] = v0 * v0 + v1 * v1 + v2 * v2;
    __syncthreads();
    for (int o = 128; o > 0; o >>= 1) {
        if (t < o) { rs[t] += rs[t + o]; rq[t] += rq[t + o]; }
        __syncthreads();
    }
    float mean = rs[0] * (1.0f / D_);
    float var = fmaxf(rq[0] * (1.0f / D_) - mean * mean, 0.f);
    float inv = rsqrtf(var + EPS_);
    float* dst = (s == 0) ? out + (size_t)B_ * N_ * D_ + (size_t)bb * D_
                          : out + ((size_t)bb * N_ + (s - 1)) * D_;
    dst[t]       = (v0 - mean) * inv * g[t]       + b[t];
    dst[t + 256] = (v1 - mean) * inv * g[t + 256] + b[t + 256];
    dst[t + 512] = (v2 - mean) * inv * g[t + 512] + b[t + 512];
}

// ---------------------------------------------------------------- MFMA GEMM (bf16 x bf16)
// C[m,n] = sum_k A[m,k] * W[n,k] + bias[n]
// Round-3 proven structure: 128x128 tile, BK=32, depth-1 double-buffered
// global_load_lds (prefetch t+1 while computing t, ONE __syncthreads per
// K-step), 32 KB LDS -> 2+ blocks/CU.
// Adds vs round 3 (both independently verified in round 4):
//  * XOR-granule swizzle: gload_lds writes linearly, so the global SOURCE
//    16B-granule is permuted per lane (cg ^ ((lane>>3)&3)) and the ds_read
//    granule applies the same XOR (quad ^ ((col>>1)&3)) -> bank conflicts
//    4.79M -> 0 on this exact layout.
//  * n-fast block order inside bijective XCD chunks: consecutive blocks in
//    one XCD share the A-panel (0.2 MB, L2-hot) and stream W once.
// MODE 0: plain  2: exact gelu  3: + res[m,n] (f32)
// A rows >= M are read (garbage, within workspace) but never stored.
template <typename TC, int MODE>
__global__ __launch_bounds__(256) void mgemm(
    const bf16* __restrict__ A, const bf16* __restrict__ W,
    const float* __restrict__ bias, const float* __restrict__ res,
    TC* __restrict__ C, int M, int N, int K)
{
    __shared__ short As[2][128 * 32];
    __shared__ short Ws[2][128 * 32];
    AS3 short* AsL = (AS3 short*)&As[0][0];
    AS3 short* WsL = (AS3 short*)&Ws[0][0];
    const int t = threadIdx.x;
    const int lane = t & 63;
    const int w = t >> 6;
    const int wm = w & 1, wn = w >> 1;
    const int quad = lane >> 4;
    const int col = lane & 15;

    // bijective XCD swizzle, n-fast within chunks
    const int nwg = gridDim.x;
    const int orig = blockIdx.x;
    const int q8 = nwg >> 3, r8 = nwg & 7;
    const int xcd = orig & 7, li = orig >> 3;
    const int wgid = (xcd < r8 ? xcd * (q8 + 1) : r8 * (q8 + 1) + (xcd - r8) * q8) + li;
    const int gnx = N >> 7;                 // n-tiles
    const int block_n = (wgid % gnx) * 128;
    const int block_m = (wgid / gnx) * 128;

    const int lrow = lane >> 2;             // 0..15 within 16-row segment
    // SOURCE granule permutation: physical slot (lane&3) of its row receives
    // logical granule (lane&3) ^ ((row>>1)&3); (row>>1)&3 == (lane>>3)&3.
    const int lcol = ((lane & 3) ^ ((lane >> 3) & 3)) * 8;   // shorts

    auto stage = [&](int buf, int k0) {
        #pragma unroll
        for (int ss = 0; ss < 2; ss++) {
            int seg = w * 2 + ss;                 // 0..7, wave-uniform
            int row = seg * 16 + lrow;
            const bf16* ga = A + (size_t)(block_m + row) * K + k0 + lcol;
            __builtin_amdgcn_global_load_lds((const AS1 void*)ga,
                (AS3 void*)(AsL + buf * (128 * 32) + seg * 512), 16, 0, 0);
            const bf16* gw = W + (size_t)(block_n + row) * K + k0 + lcol;
            __builtin_amdgcn_global_load_lds((const AS1 void*)gw,
                (AS3 void*)(WsL + buf * (128 * 32) + seg * 512), 16, 0, 0);
        }
    };

    f32x4 acc[4][4];
    #pragma unroll
    for (int i = 0; i < 4; i++)
        #pragma unroll
        for (int j = 0; j < 4; j++)
            acc[i][j] = (f32x4){0.f, 0.f, 0.f, 0.f};

    // READ granule permutation (matches source): row = 16*mt + col, so
    // (row>>1)&3 == (col>>1)&3 (thread-constant).
    const int qs = (quad ^ ((col >> 1) & 3)) * 8;   // shorts

    const int nt = K >> 5;
    stage(0, 0);
    __syncthreads();
    int cur = 0;
    for (int tt = 0; tt < nt; tt++) {
        if (tt + 1 < nt) stage(cur ^ 1, (tt + 1) << 5);  // prefetch next tile
        bf16x8 af[4], bfr[4];
        #pragma unroll
        for (int mt = 0; mt < 4; mt++)
            af[mt] = *(const bf16x8*)&As[cur][(wm * 64 + mt * 16 + col) * 32 + qs];
        #pragma unroll
        for (int ntt = 0; ntt < 4; ntt++)
            bfr[ntt] = *(const bf16x8*)&Ws[cur][(wn * 64 + ntt * 16 + col) * 32 + qs];
        #pragma unroll
        for (int mt = 0; mt < 4; mt++)
            #pragma unroll
            for (int ntt = 0; ntt < 4; ntt++)
                acc[mt][ntt] = __builtin_amdgcn_mfma_f32_16x16x32_bf16(
                    af[mt], bfr[ntt], acc[mt][ntt], 0, 0, 0);
        __syncthreads();   // drains vmcnt(0)+lgkmcnt(0): prefetch landed, reads done
        cur ^= 1;
    }

    // epilogue: D row = quad*4 + r, col = lane&15
    #pragma unroll
    for (int mt = 0; mt < 4; mt++) {
        #pragma unroll
        for (int ntt = 0; ntt < 4; ntt++) {
            int gn = block_n + wn * 64 + ntt * 16 + col;
            float bn = bias[gn];
            #pragma unroll
            for (int r = 0; r < 4; r++) {
                int gm = block_m + wm * 64 + mt * 16 + quad * 4 + r;
                if (gm < M) {
                    float val = acc[mt][ntt][r] + bn;
                    if (MODE == 2) val = 0.5f * val * (1.0f + erff(val * 0.70710678118654752f));
                    if (MODE == 3) val += res[(size_t)gm * N + gn];
                    C[(size_t)gm * N + gn] = (TC)val;
                }
            }
        }
    }
}

// ---------------------------------------------------------------- MFMA flash attention
// grid (5 q-tiles of 64, B*H). 4 waves/block, each wave owns 16 q rows.
// Q/K/V live in the fused qkv buffer: row stride QKVN_, offsets 0/768/1536.
__global__ __launch_bounds__(256) void attn_mfma(
    const bf16* __restrict__ qkv, const bf16* __restrict__ bias,
    bf16* __restrict__ ob)
{
    const bf16* qb = qkv;
    const bf16* kb = qkv + D_;
    const bf16* vb = qkv + 2 * D_;
    // stride 72 shorts = 144 B rows: 16B-aligned b128 frags, even bank spread
    __shared__ short Ks[64 * 72];        // K[k_loc][d]
    __shared__ short Vt[64 * 72];        // V^T[d][k_loc]
    __shared__ short Ps[4][16 * 72];     // per-wave P tile [q_loc][k_loc]

    const int t = threadIdx.x;
    const int lane = t & 63;
    const int wq = t >> 6;               // wave id = q sub-tile
    const int quad = lane >> 4;
    const int col = lane & 15;
    const int bh = blockIdx.y;
    const int hh = bh % H_;
    const int b = bh / H_;
    const int q0 = blockIdx.x * 64;

    // ---- Q fragments: A-operand row = col (q in tile), k-offset = quad*8 + kk*32
    bf16x8 qf[2];
    {
        int qrow = q0 + wq * 16 + col;
        #pragma unroll
        for (int kk = 0; kk < 2; kk++) {
            bf16x8 v = (bf16x8){0, 0, 0, 0, 0, 0, 0, 0};
            if (qrow < S_)
                v = *(const bf16x8*)(qb + ((size_t)(b * S_ + qrow)) * QKVN_ + hh * HD_ + kk * 32 + quad * 8);
            qf[kk] = v;
        }
    }

    f32x4 o_acc[4];
    #pragma unroll
    for (int nt = 0; nt < 4; nt++) o_acc[nt] = (f32x4){0.f, 0.f, 0.f, 0.f};
    float m_run[4], l_run[4];
    #pragma unroll
    for (int r = 0; r < 4; r++) { m_run[r] = NEG_BIG_; l_run[r] = 0.f; }

    for (int kc = 0; kc < 5; kc++) {
        const int kbase = kc * 64;
        // ---- stage K chunk (64 rows x 64 d), zero-fill OOR rows
        #pragma unroll
        for (int ss = 0; ss < 2; ss++) {
            int s = t + ss * 256;
            int row = s >> 3, dg = (s & 7) * 8;
            int gk = kbase + row;
            bf16x8 v = (bf16x8){0, 0, 0, 0, 0, 0, 0, 0};
            if (gk < S_)
                v = *(const bf16x8*)(kb + ((size_t)(b * S_ + gk)) * QKVN_ + hh * HD_ + dg);
            *(bf16x8*)&Ks[row * 72 + dg] = v;
        }
        // ---- stage V^T: lane -> (d = wq*16 + col, kp = ss*4 + quad), 2 keys / b32
        {
            int d = wq * 16 + col;
            const bf16* vcol = vb + ((size_t)(b * S_)) * QKVN_ + hh * HD_ + d;
            #pragma unroll
            for (int ss = 0; ss < 8; ss++) {
                int kp = ss * 4 + quad;          // 0..31
                int gk = kbase + kp * 2;
                short v0 = (gk     < S_) ? *(const short*)(vcol + (size_t)gk * QKVN_)       : (short)0;
                short v1 = (gk + 1 < S_) ? *(const short*)(vcol + (size_t)(gk + 1) * QKVN_) : (short)0;
                unsigned pk = ((unsigned)(unsigned short)v0) |
                              ((unsigned)(unsigned short)v1 << 16);
                *(unsigned*)&Vt[d * 72 + kp * 2] = pk;
            }
        }
        __syncthreads();

        // ---- S = Q K^T (contract over d)
        f32x4 s_acc[4];
        #pragma unroll
        for (int nt = 0; nt < 4; nt++) s_acc[nt] = (f32x4){0.f, 0.f, 0.f, 0.f};
        #pragma unroll
        for (int nt = 0; nt < 4; nt++) {
            #pragma unroll
            for (int kk = 0; kk < 2; kk++) {
                bf16x8 kfrag = *(const bf16x8*)&Ks[(nt * 16 + col) * 72 + kk * 32 + quad * 8];
                s_acc[nt] = __builtin_amdgcn_mfma_f32_16x16x32_bf16(qf[kk], kfrag, s_acc[nt], 0, 0, 0);
            }
        }

        // ---- bias + OOR key mask (C layout: row = quad*4+r, col = k in tile)
        const int qrow_base = q0 + wq * 16 + quad * 4;
        #pragma unroll
        for (int nt = 0; nt < 4; nt++) {
            int kglob = kbase + nt * 16 + col;
            #pragma unroll
            for (int r = 0; r < 4; r++) {
                int q = qrow_base + r;
                float sv = s_acc[nt][r];
                if (kglob >= S_)       sv = NEG_BIG_;
                else if (q < S_)       sv += b2f(bias[((size_t)bh * S_ + q) * S_ + kglob]);
                s_acc[nt][r] = sv;
            }
        }

        // ---- online softmax: rows live on the 16 lanes sharing quad
        float alpha[4];
        #pragma unroll
        for (int r = 0; r < 4; r++) {
            float mx = fmaxf(fmaxf(s_acc[0][r], s_acc[1][r]),
                             fmaxf(s_acc[2][r], s_acc[3][r]));
            #pragma unroll
            for (int off = 8; off; off >>= 1) mx = fmaxf(mx, __shfl_xor(mx, off));
            float m_new = fmaxf(m_run[r], mx);
            alpha[r] = __expf(m_run[r] - m_new);
            m_run[r] = m_new;
            float ps = 0.f;
            #pragma unroll
            for (int nt = 0; nt < 4; nt++) {
                float p = __expf(s_acc[nt][r] - m_new);
                s_acc[nt][r] = p;
                ps += p;
            }
            #pragma unroll
            for (int off = 8; off; off >>= 1) ps += __shfl_xor(ps, off);
            l_run[r] = l_run[r] * alpha[r] + ps;
        }

        // ---- P -> per-wave LDS (wave-synchronous write->read), rescale O
        #pragma unroll
        for (int nt = 0; nt < 4; nt++)
            #pragma unroll
            for (int r = 0; r < 4; r++)
                Ps[wq][(quad * 4 + r) * 72 + nt * 16 + col] = f2b(s_acc[nt][r]);
        #pragma unroll
        for (int nt = 0; nt < 4; nt++)
            #pragma unroll
            for (int r = 0; r < 4; r++)
                o_acc[nt][r] *= alpha[r];

        // ---- O += P V (contract over k; B-operand = V^T rows = d)
        bf16x8 pf[2];
        pf[0] = *(const bf16x8*)&Ps[wq][col * 72 + quad * 8];
        pf[1] = *(const bf16x8*)&Ps[wq][col * 72 + 32 + quad * 8];
        #pragma unroll
        for (int nt = 0; nt < 4; nt++) {
            #pragma unroll
            for (int kk = 0; kk < 2; kk++) {
                bf16x8 vfrag = *(const bf16x8*)&Vt[(nt * 16 + col) * 72 + kk * 32 + quad * 8];
                o_acc[nt] = __builtin_amdgcn_mfma_f32_16x16x32_bf16(pf[kk], vfrag, o_acc[nt], 0, 0, 0);
            }
        }
        __syncthreads();
    }

    // ---- epilogue: O / l  (bf16 out, stride D_)
    const int qrow_base = q0 + wq * 16 + quad * 4;
    #pragma unroll
    for (int r = 0; r < 4; r++) {
        int q = qrow_base + r;
        if (q >= S_) continue;
        float invl = 1.0f / l_run[r];
        bf16* orow = ob + ((size_t)(b * S_ + q)) * D_ + hh * HD_;
        #pragma unroll
        for (int nt = 0; nt < 4; nt++)
            orow[nt * 16 + col] = __float2bfloat16(o_acc[nt][r] * invl);
    }
}

// ---------------------------------------------------------------- launch
extern "C" void kernel_launch(void* const* d_in, const int* in_sizes, int n_in,
                              void* d_out, int out_size, void* d_ws, size_t ws_size,
                              hipStream_t stream)
{
    const int*   x         = (const int*)d_in[0];
    const float* attn_bias = (const float*)d_in[1];
    const int*   spatial   = (const int*)d_in[2];
    const int*   edget     = (const int*)d_in[3];
    const int*   indeg     = (const int*)d_in[4];
    const int*   outdeg    = (const int*)d_in[5];
    const float* atom_emb  = (const float*)d_in[6];
    const float* ine       = (const float*)d_in[7];
    const float* oute      = (const float*)d_in[8];
    const float* gtok      = (const float*)d_in[9];
    const float* spemb     = (const float*)d_in[10];
    const float* eemb      = (const float*)d_in[11];
    const float* virt      = (const float*)d_in[12];
    const float* Wq        = (const float*)d_in[13];
    const float* Wk        = (const float*)d_in[14];
    const float* Wv        = (const float*)d_in[15];
    const float* Wo        = (const float*)d_in[16];
    const float* bq        = (const float*)d_in[17];
    const float* bk        = (const float*)d_in[18];
    const float* bvv       = (const float*)d_in[19];
    const float* bo        = (const float*)d_in[20];
    const float* ln1g      = (const float*)d_in[21];
    const float* ln1b      = (const float*)d_in[22];
    const float* ln2g      = (const float*)d_in[23];
    const float* ln2b      = (const float*)d_in[24];
    const float* W1        = (const float*)d_in[25];
    const float* b1        = (const float*)d_in[26];
    const float* W2        = (const float*)d_in[27];
    const float* b2        = (const float*)d_in[28];
    const float* fing      = (const float*)d_in[29];
    const float* finb      = (const float*)d_in[30];

    const int M = B_ * S_;          // 8224
    char* wsp = (char*)d_ws;
    size_t off = 0;
    auto alloc = [&](size_t bytes) -> void* {
        void* p = (void*)(wsp + off);
        off += (bytes + 255) & ~(size_t)255;
        return p;
    };
    // ws: h 25.3 + z 12.6 + qkv/ff 50.6 + bias 50.7 + wbf 14.2 + bqkv = ~153 MB
    float* h    = (float*)alloc((size_t)M * D_ * 4);
    bf16*  z    = (bf16*)alloc((size_t)M * D_ * 2);        // also obuf (bf16)
    bf16*  qkv  = (bf16*)alloc((size_t)M * FF_ * 2);       // fused q|k|v, reused as fbuf
    bf16*  bias = (bf16*)alloc((size_t)B_ * H_ * S_ * S_ * 2);
    bf16*  wbf  = (bf16*)alloc((size_t)WTOT_ * 2);         // per-layer bf16 weights
    float* bqkv = (float*)alloc((size_t)QKVN_ * 4);        // packed q|k|v bias
    bf16* fbuf = qkv;                                      // qkv dead after attn
    bf16* obuf = z;                                        // z dead after QKV GEMM

    embed_kernel<<<M, 256, 0, stream>>>(x, indeg, outdeg, atom_emb, ine, oute, gtok, h);
    bias_kernel<<<M, 256, 0, stream>>>(x, attn_bias, spatial, edget, spemb, eemb, virt, bias);

    const int gx = (M + 127) / 128;        // 65
    const int nQKV = gx * (QKVN_ / 128);   // 65 x 18 = 1170
    const int nD   = gx * (D_ / 128);      // 65 x 6  = 390
    const int nF   = gx * (FF_ / 128);     // 65 x 24 = 1560
    dim3 gA(5, B_ * H_);                   // 5 q-tiles of 64 x 384
    const int cvtBlocks = WTOT_ / 2048;    // 3456

    for (int l = 0; l < L_; l++) {
        cvt_w_kernel<<<cvtBlocks, 256, 0, stream>>>(Wq, Wk, Wv, Wo, W1, W2, l, wbf);
        pack_bias_kernel<<<9, 256, 0, stream>>>(bq, bk, bvv, l, bqkv);
        ln_kernel<<<M, 256, 0, stream>>>(h, z, ln1g + l * D_, ln1b + l * D_);
        // fused QKV: W = [Wq*SCALE ; Wk ; Wv] rows, N = 2304
        mgemm<bf16, 0><<<nQKV, 256, 0, stream>>>(z, wbf, bqkv, nullptr, qkv, M, QKVN_, D_);
        attn_mfma<<<gA, 256, 0, stream>>>(qkv, bias, obuf);
        mgemm<float, 3><<<nD, 256, 0, stream>>>(obuf, wbf + 3 * DD_, bo + l * D_, h, h, M, D_, D_);
        ln_kernel<<<M, 256, 0, stream>>>(h, z, ln2g + l * D_, ln2b + l * D_);
        mgemm<bf16, 2><<<nF, 256, 0, stream>>>(z, wbf + 4 * DD_, b1 + l * FF_, nullptr, fbuf, M, FF_, D_);
        mgemm<float, 3><<<nD, 256, 0, stream>>>(fbuf, wbf + 4 * DD_ + FD_, b2 + l * D_, h, h, M, D_, FF_);
    }
    final_ln_kernel<<<M, 256, 0, stream>>>(h, fing, finb, (float*)d_out);
}